// Round 9
// baseline (269.939 us; speedup 1.0000x reference)
//
#include <hip/hip_runtime.h>

#define NN 100000
#define NE 1600000
#define NBUCK 196       // ceil(NN/512) buckets of 512 nodes
#define BUCKCAP 11520   // packed-pair slots per bucket (avg 8192, +36 sigma)
#define SCAP 13312      // ssrc slots per bucket (>= bucket_total + 7*512 at +17 sigma)
#define ACHUNK 8192     // edges per partition block

typedef _Float16 f16x8 __attribute__((ext_vector_type(8)));
typedef float f32x4 __attribute__((ext_vector_type(4)));

// ---------------- workspace layout (bytes) ----------------
static const size_t OFF_GCUR  = 0;                         // 256 ints
static const size_t OFF_META  = 1024;                      // NN int4 {beg, padded_deg, inv_deg bits, 0}
static const size_t OFF_SSRC  = 1601024;                   // NBUCK*SCAP ints = 10.4MB
static const size_t OFF_PAIRS = 12037632;                  // NBUCK*BUCKCAP ints = 9.0MB
static const size_t OFF_B1    = 21069312;                  // 128x256 f16
static const size_t OFF_B2    = 21134848;
static const size_t OFF_X16   = 21200384;                  // (N+1)*128 f16 (row N = zeros)
static const size_t OFF_H16   = 46800640;                  // (N+1)*128 f16 (row N = zeros)
// end 72.4MB

static __device__ inline float h2f(uint bits) {
    return (float)__builtin_bit_cast(_Float16, (ushort)bits);
}
static __device__ inline ushort f2h(float f) {
    return __builtin_bit_cast(ushort, (_Float16)f);
}
static __device__ inline uint pk2h(float a, float b) {
    return (uint)f2h(a) | ((uint)f2h(b) << 16);
}

__global__ void zero_dummy(ushort* __restrict__ a, ushort* __restrict__ b) {
    int t = threadIdx.x;
    a[(size_t)NN * 128 + t] = 0;
    b[(size_t)NN * 128 + t] = 0;
}

__global__ void init_gcur(int* __restrict__ gcur) {
    gcur[threadIdx.x] = threadIdx.x * BUCKCAP;
}

// single-pass radix partition: LDS-reorder each 8192-edge chunk bucket-contiguously,
// stream out dense runs of packed (src<<9 | dst&511) ints
__global__ __launch_bounds__(256) void partition_pairs(const int* __restrict__ src,
                                                       const int* __restrict__ dst,
                                                       int* __restrict__ gcur,
                                                       int* __restrict__ pairs, int ne) {
    __shared__ int2 staged[ACHUNK];   // 64KB {packed, dst}
    __shared__ int  dcache[ACHUNK];   // 32KB
    __shared__ int  hist[256], scanb[256], gbase[256];
    const int t = threadIdx.x;
    const int base = blockIdx.x * ACHUNK;
    const int n = min(ACHUNK, ne - base);

    hist[t] = 0;
    __syncthreads();
    for (int i = t; i < n; i += 256) {
        int d = dst[base + i];
        dcache[i] = d;
        atomicAdd(&hist[d >> 9], 1);
    }
    __syncthreads();

    int v = hist[t];
    scanb[t] = v;
    __syncthreads();
    for (int off = 1; off < 256; off <<= 1) {
        int x = (t >= off) ? scanb[t - off] : 0;
        __syncthreads();
        scanb[t] += x;
        __syncthreads();
    }
    int excl = scanb[t] - v;
    __syncthreads();
    scanb[t] = excl;
    hist[t] = 0;
    gbase[t] = (v > 0) ? atomicAdd(&gcur[t], v) : 0;
    __syncthreads();

    for (int i = t; i < n; i += 256) {
        int d = dcache[i];
        int b = d >> 9;
        int lp = scanb[b] + atomicAdd(&hist[b], 1);
        int2 pr;
        pr.x = (src[base + i] << 9) | (d & 511);
        pr.y = d;
        staged[lp] = pr;
    }
    __syncthreads();

    for (int i = t; i < n; i += 256) {
        int2 pr = staged[i];
        int b = pr.y >> 9;
        pairs[gbase[b] + (i - scanb[b])] = pr.x;
    }
}

// one block per bucket: LDS histogram -> scan -> meta -> pad-fill -> window-local scatter
__global__ __launch_bounds__(512) void bucket_build(const int* __restrict__ gcur,
                                                    const int* __restrict__ pairs,
                                                    int4* __restrict__ meta,
                                                    int* __restrict__ ssrc) {
    __shared__ int s[512];
    __shared__ int exclA[512];
    __shared__ int cur[512];
    const int b = blockIdx.x;
    const int t = threadIdx.x;
    const int pbeg = b * BUCKCAP;
    const int pend = gcur[b];
    const int sbase = b * SCAP;

    cur[t] = 0;
    __syncthreads();
    for (int i = pbeg + t; i < pend; i += 512)
        atomicAdd(&cur[pairs[i] & 511], 1);
    __syncthreads();

    const int deg = cur[t];
    const int pc = (deg + 7) & ~7;
    s[t] = pc;
    __syncthreads();
    for (int off = 1; off < 512; off <<= 1) {
        int x = (t >= off) ? s[t - off] : 0;
        __syncthreads();
        s[t] += x;
        __syncthreads();
    }
    const int excl = s[t] - pc;
    exclA[t] = excl;
    const int node = (b << 9) + t;
    if (node < NN) {
        int4 m;
        m.x = sbase + excl;
        m.y = pc;
        m.z = __builtin_bit_cast(int, 1.0f / (float)(deg > 1 ? deg : 1));
        m.w = 0;
        meta[node] = m;
    }
    __syncthreads();
    const int total = s[511];
    for (int i = t; i < total; i += 512)
        ssrc[sbase + i] = NN;
    cur[t] = 0;
    __syncthreads();
    for (int i = pbeg + t; i < pend; i += 512) {
        int p = pairs[i];
        int loc = p & 511;
        int pos = atomicAdd(&cur[loc], 1);
        ssrc[sbase + exclA[loc] + pos] = p >> 9;
    }
}

// fp32 [n][128] -> f16 [n][128]
__global__ void to_f16(const float* __restrict__ in, ushort* __restrict__ out, int n4) {
    int i = blockIdx.x * blockDim.x + threadIdx.x;
    if (i < n4) {
        float4 v = ((const float4*)in)[i];
        uint2 o;
        o.x = pk2h(v.x, v.y);
        o.y = pk2h(v.z, v.w);
        ((uint2*)out)[i] = o;
    }
}

// pack [Wl;Wr] into Bt f16 [n][k'=256]
__global__ void prep_w(const float* __restrict__ Wl, const float* __restrict__ Wr,
                       ushort* __restrict__ Bt) {
    int id = blockIdx.x * blockDim.x + threadIdx.x;
    if (id >= 32768) return;
    int nw = id & 127;
    int km = id >> 7;
    const float* W = (km < 128) ? Wl : Wr;
    int k = km & 127;
    Bt[(size_t)nw * 256 + km] = f2h(W[k * 128 + nw]);
}

// ---- fused layer body: gather 128 nodes' mean into swizzled LDS (phase 1),
//      then C = [agg | feat_rows] @ Bt via MFMA with LDS-A (agg) + direct-global
//      A (feat) and direct-global B fragments (phase 2). smem = 32KB.
#define FUSED_BODY(FEAT)                                                               \
    const int t = threadIdx.x;                                                         \
    const int l = t & 63;                                                              \
    const int w = t >> 6;                                                              \
    const int rowBase = blockIdx.x * 128;                                              \
    /* ---- phase 1: gather+mean 32 nodes per wave into swizzled LDS ---- */           \
    {                                                                                  \
        const int nodeBase = rowBase + w * 32;                                         \
        for (int i = 0; i < 32; ++i) {                                                 \
            const int node = nodeBase + i;                                             \
            const int r = w * 32 + i;                                                  \
            float s0 = 0.f, s1 = 0.f, s2 = 0.f, s3 = 0.f,                              \
                  s4 = 0.f, s5 = 0.f, s6 = 0.f, s7 = 0.f;                              \
            float id = 0.f;                                                            \
            if (node < n) {                                                            \
                const int4 m = meta[node];                                             \
                id = __builtin_bit_cast(float, m.z);                                   \
                int e = m.x;                                                           \
                const int end = m.x + m.y;                                             \
                const size_t loff = (size_t)(l * 2);                                   \
                if (e < end) {                                                         \
                    int4 c0 = *(const int4*)(ssrc + e);                                \
                    int4 c1 = *(const int4*)(ssrc + e + 4);                            \
                    for (; e < end; e += 8) {                                          \
                        int4 d0 = c0, d1 = c1;                                         \
                        int pn = (e + 8 < end) ? e + 8 : e;                            \
                        c0 = *(const int4*)(ssrc + pn);                                \
                        c1 = *(const int4*)(ssrc + pn + 4);                            \
                        uint v0 = *(const uint*)(FEAT + (size_t)d0.x * 128 + loff);    \
                        uint v1 = *(const uint*)(FEAT + (size_t)d0.y * 128 + loff);    \
                        uint v2 = *(const uint*)(FEAT + (size_t)d0.z * 128 + loff);    \
                        uint v3 = *(const uint*)(FEAT + (size_t)d0.w * 128 + loff);    \
                        uint v4 = *(const uint*)(FEAT + (size_t)d1.x * 128 + loff);    \
                        uint v5 = *(const uint*)(FEAT + (size_t)d1.y * 128 + loff);    \
                        uint v6 = *(const uint*)(FEAT + (size_t)d1.z * 128 + loff);    \
                        uint v7 = *(const uint*)(FEAT + (size_t)d1.w * 128 + loff);    \
                        s0 += h2f(v0 & 0xffffu); s1 += h2f(v0 >> 16);                  \
                        s2 += h2f(v1 & 0xffffu); s3 += h2f(v1 >> 16);                  \
                        s0 += h2f(v2 & 0xffffu); s1 += h2f(v2 >> 16);                  \
                        s2 += h2f(v3 & 0xffffu); s3 += h2f(v3 >> 16);                  \
                        s4 += h2f(v4 & 0xffffu); s5 += h2f(v4 >> 16);                  \
                        s6 += h2f(v5 & 0xffffu); s7 += h2f(v5 >> 16);                  \
                        s4 += h2f(v6 & 0xffffu); s5 += h2f(v6 >> 16);                  \
                        s6 += h2f(v7 & 0xffffu); s7 += h2f(v7 >> 16);                  \
                    }                                                                  \
                }                                                                      \
            }                                                                          \
            *(uint*)(smem + r * 256 + ((l * 4) ^ ((r & 7) << 4))) =                    \
                pk2h((s0 + s2 + s4 + s6) * id, (s1 + s3 + s5 + s7) * id);              \
        }                                                                              \
    }                                                                                  \
    __syncthreads();                                                                   \
    /* ---- phase 2: MFMA K'=256 (agg from LDS, feat + B direct global) ---- */        \
    const int wr = (w >> 1) * 64, wc = (w & 1) * 64;                                   \
    f32x4 acc[4][4];                                                                   \
    _Pragma("unroll")                                                                  \
    for (int i = 0; i < 4; ++i)                                                        \
        _Pragma("unroll")                                                              \
        for (int j = 0; j < 4; ++j) acc[i][j] = 0.0f;                                  \
    _Pragma("unroll")                                                                  \
    for (int kc = 0; kc < 8; ++kc) {                                                   \
        f16x8 af[4], bf[4];                                                            \
        _Pragma("unroll")                                                              \
        for (int i = 0; i < 4; ++i) {                                                  \
            const int r = wr + i * 16 + (l & 15);                                      \
            if (kc < 4) {                                                              \
                af[i] = *(const f16x8*)(smem + r * 256 +                               \
                         ((kc * 64 + (l >> 4) * 16) ^ ((r & 7) << 4)));                \
            } else {                                                                   \
                int grow = rowBase + r;                                                \
                if (grow >= n) grow = n - 1;                                           \
                af[i] = *(const f16x8*)(FEAT + (size_t)grow * 128 +                    \
                                        (kc - 4) * 32 + (l >> 4) * 8);                 \
            }                                                                          \
            const int cn = wc + i * 16 + (l & 15);                                     \
            bf[i] = *(const f16x8*)(Bt + (size_t)cn * 256 + kc * 32 + (l >> 4) * 8);   \
        }                                                                              \
        _Pragma("unroll")                                                              \
        for (int i = 0; i < 4; ++i)                                                    \
            _Pragma("unroll")                                                          \
            for (int j = 0; j < 4; ++j)                                                \
                acc[i][j] = __builtin_amdgcn_mfma_f32_16x16x32_f16(af[i], bf[j],       \
                                                                   acc[i][j], 0, 0, 0); \
    }

// layer 1: h16 = relu(mean_agg(x16)@W1l + x16@W1r + b1), coalesced f16 store
__global__ __launch_bounds__(256, 4) void fused_layer1(const ushort* __restrict__ feat,
                                                       const int4* __restrict__ meta,
                                                       const int* __restrict__ ssrc,
                                                       const ushort* __restrict__ Bt,
                                                       const float* __restrict__ bias,
                                                       ushort* __restrict__ outH, int n) {
    __shared__ __align__(16) char smem[32768];
    FUSED_BODY(feat)

    __syncthreads();
    ushort* sOut = (ushort*)smem;
#pragma unroll
    for (int j = 0; j < 4; ++j) {
        int col = wc + j * 16 + (l & 15);
        float bb = bias[col];
#pragma unroll
        for (int i = 0; i < 4; ++i)
#pragma unroll
            for (int q = 0; q < 4; ++q) {
                int row = wr + i * 16 + (l >> 4) * 4 + q;
                sOut[row * 128 + col] = f2h(fmaxf(acc[i][j][q] + bb, 0.f));
            }
    }
    __syncthreads();
    // full 32KB tile: 8 passes x 256 threads x 16B, coalesced
#pragma unroll
    for (int k = 0; k < 8; ++k) {
        int row = k * 16 + (t >> 4);
        int4 v = *(const int4*)(smem + k * 4096 + t * 16);
        if (rowBase + row < n)
            *(int4*)(outH + (size_t)(rowBase + row) * 128 + (t & 15) * 8) = v;
    }
}

// layer 2 + final linear: out = relu(mean_agg(h16)@W2l + h16@W2r + b2) @ Wlin + blin
__global__ __launch_bounds__(256, 4) void fused_layer2(const ushort* __restrict__ feat,
                                                       const int4* __restrict__ meta,
                                                       const int* __restrict__ ssrc,
                                                       const ushort* __restrict__ Bt,
                                                       const float* __restrict__ bias,
                                                       const float* __restrict__ Wlin,
                                                       const float* __restrict__ blin,
                                                       float* __restrict__ out, int n) {
    __shared__ __align__(16) char smem[32768];
    FUSED_BODY(feat)

    // per-thread partial dot with Wlin over its 4 columns
    float bb[4], wl0[4], wl1[4];
#pragma unroll
    for (int j = 0; j < 4; ++j) {
        int col = wc + j * 16 + (l & 15);
        bb[j]  = bias[col];
        float2 wv = *(const float2*)&Wlin[col * 2];
        wl0[j] = wv.x;
        wl1[j] = wv.y;
    }
    __syncthreads();
    float* sP = (float*)smem;   // [128 rows][32 slots][2] = 32KB
    const int p = (w & 1) * 16 + (l & 15);
#pragma unroll
    for (int i = 0; i < 4; ++i)
#pragma unroll
        for (int q = 0; q < 4; ++q) {
            int row = wr + i * 16 + (l >> 4) * 4 + q;
            float p0 = 0.f, p1 = 0.f;
#pragma unroll
            for (int j = 0; j < 4; ++j) {
                float v = fmaxf(acc[i][j][q] + bb[j], 0.f);
                p0 += v * wl0[j];
                p1 += v * wl1[j];
            }
            int sidx = (p + row) & 31;   // row-keyed slot swizzle (store side)
            sP[row * 64 + sidx * 2 + 0] = p0;
            sP[row * 64 + sidx * 2 + 1] = p1;
        }
    __syncthreads();

    // 256 threads reduce 256 outputs; read slots row-rotated -> conflict-free
    const int row = t >> 1, comp = t & 1;
    float s = 0.f;
#pragma unroll
    for (int k = 0; k < 32; ++k)
        s += sP[row * 64 + (((k + row) & 31)) * 2 + comp];
    if (rowBase + row < n)
        out[(size_t)(rowBase + row) * 2 + comp] = s + blin[comp];
}

extern "C" void kernel_launch(void* const* d_in, const int* in_sizes, int n_in,
                              void* d_out, int out_size, void* d_ws, size_t ws_size,
                              hipStream_t stream) {
    const float* x    = (const float*)d_in[0];
    const int*   ei   = (const int*)d_in[1];
    const float* W1l  = (const float*)d_in[2];
    const float* b1   = (const float*)d_in[3];
    const float* W1r  = (const float*)d_in[4];
    const float* W2l  = (const float*)d_in[5];
    const float* b2   = (const float*)d_in[6];
    const float* W2r  = (const float*)d_in[7];
    const float* Wlin = (const float*)d_in[8];
    const float* blin = (const float*)d_in[9];
    float* out = (float*)d_out;

    char* ws = (char*)d_ws;
    int*    gcur    = (int*)(ws + OFF_GCUR);
    int4*   meta    = (int4*)(ws + OFF_META);
    int*    ssrc    = (int*)(ws + OFF_SSRC);
    int*    pairs   = (int*)(ws + OFF_PAIRS);
    ushort* B1c     = (ushort*)(ws + OFF_B1);
    ushort* B2c     = (ushort*)(ws + OFF_B2);
    ushort* x16     = (ushort*)(ws + OFF_X16);
    ushort* h16     = (ushort*)(ws + OFF_H16);

    const int* src = ei;
    const int* dst = ei + NE;

    // weight packing + f16 conversion + dummy zero rows
    prep_w<<<128, 256, 0, stream>>>(W1l, W1r, B1c);
    prep_w<<<128, 256, 0, stream>>>(W2l, W2r, B2c);
    to_f16<<<(NN * 32 + 255) / 256, 256, 0, stream>>>(x, x16, NN * 32);
    zero_dummy<<<1, 128, 0, stream>>>(x16, h16);

    // CSR build: radix partition -> per-bucket LDS count/scan/fill
    init_gcur<<<1, 256, 0, stream>>>(gcur);
    partition_pairs<<<(NE + ACHUNK - 1) / ACHUNK, 256, 0, stream>>>(src, dst, gcur, pairs, NE);
    bucket_build<<<NBUCK, 512, 0, stream>>>(gcur, pairs, meta, ssrc);

    // layer 1 (fused aggregate + GEMM)
    fused_layer1<<<(NN + 127) / 128, 256, 0, stream>>>(x16, meta, ssrc, B1c, b1, h16, NN);

    // layer 2 (fused aggregate + GEMM + final linear)
    fused_layer2<<<(NN + 127) / 128, 256, 0, stream>>>(h16, meta, ssrc, B2c, b2, Wlin, blin, out, NN);
}